// Round 1
// baseline (2204.272 us; speedup 1.0000x reference)
//
#include <hip/hip_runtime.h>
#include <hip/hip_bf16.h>
#include <cstdint>

#define NT 256          // threads per block
#define TILEA 256       // atoms per conv block
#define N_ATOMS_C 600000
#define BATCH_C 24000

// degree partition (compile-time constants from the reference)
constexpr int K_COUNTS[11] = {10000,130000,170000,160000,100000,15000,5000,2500,2500,2500,2500};
constexpr int K_STARTS[11] = {0,10000,140000,310000,470000,570000,585000,590000,592500,595000,597500};

struct AdjPtrs { const int* p[10]; };

__device__ __forceinline__ float selu_f(float x) {
    const float scale = 1.0507009873554805f;
    const float alpha = 1.6732632423543772f;
    return scale * (x > 0.f ? x : alpha * expm1f(x));
}

// ---------------------------------------------------------------------------
// Conv layer: out[r] = selu( rel@Wa + self@Wb + ba + bb ), degree-blocked.
// thread = atom; activations staged in LDS strips [FS][TILEA+1]; weights read
// with wave-uniform addresses (expect s_load -> SGPR operand in v_fma).
// ---------------------------------------------------------------------------
template<int FIN, int FO, int FS>
__global__ __launch_bounds__(256) void conv_kernel(
    const float* __restrict__ x,      // (N_ATOMS, FIN)
    const float* __restrict__ W,      // (21, FIN, FO)
    const float* __restrict__ bias,   // (21, FO)
    AdjPtrs adjp,
    float* __restrict__ y)            // (N_ATOMS, FO)
{
    static_assert(FIN % FS == 0, "FS must divide FIN");
    constexpr int NSTRIP = FIN / FS;

    __shared__ float sRel[FS][TILEA + 1];
    __shared__ float sSelf[FS][TILEA + 1];
    __shared__ int   sIdx[TILEA * 10];

    const int tid = threadIdx.x;

    // block -> (degree, tile) lookup, fully compile-time table
    int blk = blockIdx.x;
    int deg = 0, s = 0, cnt = 0;
#pragma unroll
    for (int d = 0; d < 11; ++d) {
        const int nb = (K_COUNTS[d] + TILEA - 1) / TILEA;
        if (blk < nb) { deg = d; s = K_STARTS[d]; cnt = K_COUNTS[d]; break; }
        blk -= nb;
    }
    const int a0 = blk * TILEA;
    const int na = min(TILEA, cnt - a0);

    const float* Wa; const float* Wb; const float* ba; const float* bb;
    if (deg == 0) {
        Wb = W + 20 * FIN * FO; bb = bias + 20 * FO; Wa = Wb; ba = bb;
    } else {
        Wa = W + (2 * (deg - 1)) * FIN * FO;
        Wb = W + (2 * deg - 1) * FIN * FO;
        ba = bias + (2 * (deg - 1)) * FO;
        bb = bias + (2 * deg - 1) * FO;
    }

    // adjacency rows for this tile -> LDS
    if (deg > 0) {
        const int* adj = adjp.p[deg - 1] + a0 * deg;
        for (int i = tid; i < na * deg; i += NT) sIdx[i] = adj[i];
    }

    float acc[FO];
#pragma unroll
    for (int o = 0; o < FO; ++o)
        acc[o] = (deg > 0) ? (ba[o] + bb[o]) : bb[o];

    const int jc = min(tid, na - 1);      // clamped atom (keeps lanes uniform)
    const int selfbase = (s + a0) * FIN;  // fits in int (<= 45M)

    for (int strip = 0; strip < NSTRIP; ++strip) {
        const int f0 = strip * FS;
        __syncthreads();  // sIdx ready / previous strip consumed
        // stage self rows
        for (int i = tid; i < na * FS; i += NT) {
            const int j = i / FS, fs = i - j * FS;
            sSelf[fs][j] = x[selfbase + j * FIN + f0 + fs];
        }
        // stage neighbor sums
        if (deg > 0) {
            for (int i = tid; i < na * FS; i += NT) {
                const int j = i / FS, fs = i - j * FS;
                float a = 0.f;
                const int* ip = &sIdx[j * deg];
                for (int k = 0; k < deg; ++k)
                    a += x[ip[k] * FIN + f0 + fs];
                sRel[fs][j] = a;
            }
        }
        __syncthreads();
        // accumulate: weights via wave-uniform loads (SGPR), acts from LDS
        if (deg > 0) {
#pragma unroll
            for (int fs = 0; fs < FS; ++fs) {
                const float as = sSelf[fs][jc];
                const float ar = sRel[fs][jc];
                const float* wb = Wb + (f0 + fs) * FO;
                const float* wa = Wa + (f0 + fs) * FO;
#pragma unroll
                for (int o = 0; o < FO; ++o)
                    acc[o] += as * wb[o] + ar * wa[o];
            }
        } else {
#pragma unroll
            for (int fs = 0; fs < FS; ++fs) {
                const float as = sSelf[fs][jc];
                const float* wb = Wb + (f0 + fs) * FO;
#pragma unroll
                for (int o = 0; o < FO; ++o)
                    acc[o] += as * wb[o];
            }
        }
    }

    if (tid < na) {
        float* yp = y + (s + a0 + tid) * FO;
#pragma unroll
        for (int o = 0; o < FO; ++o) yp[o] = selu_f(acc[o]);
    }
}

// ---------------------------------------------------------------------------
// segment sum/max init + atomic reduce
// ---------------------------------------------------------------------------
__global__ __launch_bounds__(256) void init_kernel(float* __restrict__ sums,
                                                   unsigned* __restrict__ maxs)
{
    const int i = blockIdx.x * NT + threadIdx.x;
    if (i < BATCH_C * 36) { sums[i] = 0.f; maxs[i] = 0x007FFFFFu; } // enc(-inf)
}

__global__ __launch_bounds__(256) void gather_kernel(
    const float* __restrict__ x,          // (N_ATOMS, 36)
    const int* __restrict__ mem,          // (N_ATOMS)
    float* __restrict__ sums,             // (BATCH, 36)
    unsigned* __restrict__ maxs)          // (BATCH, 36) encoded
{
    const int idx = blockIdx.x * NT + threadIdx.x;
    if (idx >= N_ATOMS_C * 36) return;
    const int atom = idx / 36;
    const int f = idx - atom * 36;
    const float v = x[idx];
    const int m = mem[atom];
    atomicAdd(&sums[m * 36 + f], v);
    const unsigned bits = __float_as_uint(v);
    const unsigned enc = bits ^ ((bits >> 31) ? 0xFFFFFFFFu : 0x80000000u);
    atomicMax(&maxs[m * 36 + f], enc);
}

// ---------------------------------------------------------------------------
// mol = tanh([sums, maxs]); logits = mol @ Wd + bd; softmax over pairs
// ---------------------------------------------------------------------------
__global__ __launch_bounds__(256) void dense_kernel(
    const float* __restrict__ sums, const unsigned* __restrict__ maxs,
    const float* __restrict__ Wd,   // (72, 24)
    const float* __restrict__ bd,   // (24)
    float* __restrict__ out)        // (BATCH, 12, 2)
{
    __shared__ float sW[72 * 24];
    __shared__ float sb[24];
    __shared__ float sMol[64][72];

    const int tid = threadIdx.x;
    for (int i = tid; i < 72 * 24; i += NT) sW[i] = Wd[i];
    if (tid < 24) sb[tid] = bd[tid];

    const int m0 = blockIdx.x * 64;
    for (int i = tid; i < 64 * 36; i += NT) {
        const int j = i / 36, f = i - j * 36;
        const int m = m0 + j;
        if (m < BATCH_C) {
            sMol[j][f] = tanhf(sums[m * 36 + f]);
            const unsigned enc = maxs[m * 36 + f];
            const unsigned bits = (enc & 0x80000000u) ? (enc ^ 0x80000000u) : ~enc;
            sMol[j][36 + f] = tanhf(__uint_as_float(bits));
        }
    }
    __syncthreads();

    for (int i = tid; i < 64 * 12; i += NT) {
        const int j = i / 12, t = i - j * 12;
        const int m = m0 + j;
        if (m >= BATCH_C) continue;
        float l0 = sb[2 * t], l1 = sb[2 * t + 1];
#pragma unroll
        for (int f = 0; f < 72; ++f) {
            const float v = sMol[j][f];
            l0 += v * sW[f * 24 + 2 * t];
            l1 += v * sW[f * 24 + 2 * t + 1];
        }
        const float mx = fmaxf(l0, l1);
        const float e0 = expf(l0 - mx), e1 = expf(l1 - mx);
        const float inv = 1.f / (e0 + e1);
        out[m * 24 + 2 * t]     = e0 * inv;
        out[m * 24 + 2 * t + 1] = e1 * inv;
    }
}

// ---------------------------------------------------------------------------
extern "C" void kernel_launch(void* const* d_in, const int* in_sizes, int n_in,
                              void* d_out, int out_size, void* d_ws, size_t ws_size,
                              hipStream_t stream)
{
    const float* x0        = (const float*)d_in[0];
    const int*   membership= (const int*)d_in[2];
    AdjPtrs adj;
    for (int d = 0; d < 10; ++d) adj.p[d] = (const int*)d_in[3 + d];
    const float *W1=(const float*)d_in[13], *b1=(const float*)d_in[14];
    const float *W2=(const float*)d_in[15], *b2=(const float*)d_in[16];
    const float *W3=(const float*)d_in[17], *b3=(const float*)d_in[18];
    const float *W4=(const float*)d_in[19], *b4=(const float*)d_in[20];
    const float *Wd=(const float*)d_in[21], *bd=(const float*)d_in[22];

    // workspace layout (floats): bufA 600000*27, bufB 600000*36, sums, maxs
    const size_t needA = 600000ull * 27, needB = 600000ull * 36;
    const size_t needBytes = (needA + needB + 2ull * BATCH_C * 36) * 4ull;
    if (ws_size < needBytes) return;  // insufficient scratch — fail loudly

    float* bufA = (float*)d_ws;
    float* bufB = bufA + needA;
    float* sums = bufB + needB;
    unsigned* maxs = (unsigned*)(sums + BATCH_C * 36);

    int nblk = 0;
    for (int d = 0; d < 11; ++d) nblk += (K_COUNTS[d] + TILEA - 1) / TILEA;

    conv_kernel<75,15,15><<<nblk, NT, 0, stream>>>(x0,  W1, b1, adj, bufA);
    conv_kernel<15,20,15><<<nblk, NT, 0, stream>>>(bufA, W2, b2, adj, bufB);
    conv_kernel<20,27,10><<<nblk, NT, 0, stream>>>(bufB, W3, b3, adj, bufA);
    conv_kernel<27,36, 9><<<nblk, NT, 0, stream>>>(bufA, W4, b4, adj, bufB);

    init_kernel<<<(BATCH_C * 36 + NT - 1) / NT, NT, 0, stream>>>(sums, maxs);
    gather_kernel<<<(N_ATOMS_C * 36 + NT - 1) / NT, NT, 0, stream>>>(bufB, membership, sums, maxs);
    dense_kernel<<<(BATCH_C + 63) / 64, NT, 0, stream>>>(sums, maxs, Wd, bd, (float*)d_out);
}